// Round 1
// 5920.374 us; speedup vs baseline: 1.0711x; 1.0711x over previous
//
#include <hip/hip_runtime.h>
#include <stdint.h>

// Problem dims
#define Md 50
#define Kd 50
#define Vd 200
#define Ad 64
#define Bd 512
#define Sd 1024

__device__ __forceinline__ float fast_tanh(float x) {
    float e = __expf(2.f * x);
    return 1.f - 2.f / (e + 1.f);
}

__device__ __forceinline__ float sigmoidf_(float x) {
    return 1.f / (1.f + __expf(-x));
}

// wave-uniform register broadcast (replaces LDS broadcast reads)
__device__ __forceinline__ float rl(float v, int l) {
    return __uint_as_float((unsigned)__builtin_amdgcn_readlane((int)__float_as_uint(v), l));
}

// 256 blocks x 512 threads; block handles batch elements 2*blk and 2*blk+1.
// Per step (3 barriers):
//   PhaseA: waves 4-7: s4 (rc)          || waves 0-3: s5a (erase/add, a_t half)
//   PhaseB: waves 4-7: s5b (rc half)    || waves 2,3: fused softmax for t+1
//   PhaseC: s6 (mem update) ; commit a(t+1)/q(t+2) ; s3(t+1) ; w_out(t+1)
__global__ __launch_bounds__(512, 2)
void agm_kernel(const float* __restrict__ q_in,    // (B,S,K)
                const float* __restrict__ a_in,    // (B,S,A)
                const float* __restrict__ mem_in,  // (B,M,V)
                const float* __restrict__ key_in,  // (M,K)
                const float* __restrict__ Wc_in,   // (K,K)
                const float* __restrict__ bc_in,   // (K)
                const float* __restrict__ Wr_in,   // (A,V)
                const float* __restrict__ br_in,   // (A)
                const float* __restrict__ We_in,   // (V,2A)
                const float* __restrict__ be_in,   // (V)
                const float* __restrict__ Wa_in,   // (V,2A)
                const float* __restrict__ ba_in,   // (V)
                float* __restrict__ rc_out,        // (B,S,A)
                float* __restrict__ mem_out,       // (B,M,V)
                float* __restrict__ w_out)         // (B,S,M)
{
    __shared__ float sWcT[Kd * Kd];                 // WcT[k][i] = Wc[i][k]
    __shared__ float sKeyT[Kd * Md];                // keyT[k][m] = key[m][k]
    __shared__ __align__(16) float sWrT[Vd * 66];   // WrT[v*66+a] = Wr[a][v] (padded)
    __shared__ float sbc[Kd], sbr[Ad], sbe[Vd], sba[Vd];
    __shared__ float sq[2][2][Kd];                  // [parity][hb][k]
    __shared__ float sw[2][2][64];                  // [parity][hb][m]
    __shared__ __align__(16) float swi[2][128];     // [hb]: [0:64)=a_t, [64:128)=rc
    __shared__ __align__(16) float srcvI[Vd * 2];   // [v*2 + hb]
    __shared__ float spe[2][2][Vd];                 // [wh][hb][v] erase partials
    __shared__ float spa[2][2][Vd];                 // [wh][hb][v] add partials

    const int tid = threadIdx.x;
    const int blk = blockIdx.x;
    const int hb  = tid >> 8;      // batch half
    const int mv  = tid & 255;     // memory column
    const int wv  = tid >> 6;      // wave id 0..7
    const int ln  = tid & 63;      // lane
    const int bidx = blk * 2 + hb;

    // ---------- one-time preload of shared weights ----------
    for (int idx = tid; idx < Kd * Kd; idx += 512) {
        int i = idx / Kd, k = idx % Kd;
        sWcT[k * Kd + i]  = Wc_in[idx];
        sKeyT[k * Md + i] = key_in[idx];
    }
    for (int idx = tid; idx < Ad * Vd; idx += 512) {
        int a = idx / Vd, v = idx % Vd;
        sWrT[v * 66 + a] = Wr_in[idx];
    }
    if (tid < Kd) sbc[tid] = bc_in[tid];
    if (tid < Ad) sbr[tid] = br_in[tid];
    if (tid < Vd) { sbe[tid] = be_in[tid]; sba[tid] = ba_in[tid]; }

    // ---------- register-resident We/Wa half-rows (s5) ----------
    // waves 0-3: wh=0 (a_t half of wi); waves 4-7: wh=1 (rc half)
    const int wh5 = wv >> 2;
    const int r5  = (wv & 3) * 50 + ln;    // output row v, valid when ln<50
    float WeC[64], WaC[64];
    if (ln < 50) {
        const float4* wep = (const float4*)(We_in + (size_t)r5 * 128 + wh5 * 64);
        const float4* wap = (const float4*)(Wa_in + (size_t)r5 * 128 + wh5 * 64);
        #pragma unroll
        for (int c = 0; c < 16; ++c) {
            float4 ue = wep[c], ua = wap[c];
            WeC[4*c+0]=ue.x; WeC[4*c+1]=ue.y; WeC[4*c+2]=ue.z; WeC[4*c+3]=ue.w;
            WaC[4*c+0]=ua.x; WaC[4*c+1]=ua.y; WaC[4*c+2]=ua.z; WaC[4*c+3]=ua.w;
        }
    } else {
        #pragma unroll
        for (int j = 0; j < 64; ++j) { WeC[j] = 0.f; WaC[j] = 0.f; }
    }

    // ---------- s4 a-pair roles (waves 4-7) ----------
    const int g4 = (tid >> 3) & 31;   // a-pair index, valid for tid>=256
    const int c4 = tid & 7;           // v-chunk (25 wide)

    // ---------- register-resident memory column ----------
    float memcol[Md];
    if (mv < Vd) {
        #pragma unroll
        for (int m = 0; m < Md; ++m)
            memcol[m] = mem_in[(size_t)bidx * Md * Vd + m * Vd + mv];
    } else {
        #pragma unroll
        for (int m = 0; m < Md; ++m) memcol[m] = 0.f;
    }

    // ---------- q/a prefetch roles ----------
    const bool is_q = (tid < 100);
    const int qhb = tid / 50, qk = tid % 50;
    const bool is_a = (tid >= 256 && tid < 384);
    const int ahb = (tid - 256) >> 6, aj = tid & 63;

    // fused stage1+stage2: ck=tanh(q@WcT+bc); w=softmax(ck@keyT)  (one wave, no LDS scratch)
    auto fused_s1s2 = [&](int par, int h) {
        float ckv = 0.f;
        if (ln < Kd) {
            float acc = sbc[ln];
            #pragma unroll
            for (int k = 0; k < Kd; ++k)
                acc = fmaf(sq[par][h][k], sWcT[k * Kd + ln], acc);
            ckv = fast_tanh(acc);
        }
        float lg = -1e30f;
        if (ln < Md) {
            float l0 = 0.f, l1 = 0.f;
            #pragma unroll
            for (int k = 0; k < Kd; k += 2) {
                l0 = fmaf(rl(ckv, k),     sKeyT[k * Md + ln],       l0);
                l1 = fmaf(rl(ckv, k + 1), sKeyT[(k + 1) * Md + ln], l1);
            }
            lg = l0 + l1;
        }
        float mx = lg;
        #pragma unroll
        for (int off = 32; off > 0; off >>= 1)
            mx = fmaxf(mx, __shfl_xor(mx, off));
        float e = (ln < Md) ? __expf(lg - mx) : 0.f;
        float sm = e;
        #pragma unroll
        for (int off = 32; off > 0; off >>= 1)
            sm += __shfl_xor(sm, off);
        if (ln < Md) sw[par][h][ln] = e / sm;
    };

    // 64-wide erase/add partial dot for this wave's wh half; x broadcast via readlane
    auto s5dot = [&](int xoff, int whi) {
        float xA = swi[0][xoff + ln];   // all 64 lanes carry live x data
        float xB = swi[1][xoff + ln];
        float pe0 = 0.f, pa0 = 0.f, pe1 = 0.f, pa1 = 0.f;
        #pragma unroll
        for (int j = 0; j < 64; ++j) {
            float sa = rl(xA, j);
            float sb = rl(xB, j);
            pe0 = fmaf(sa, WeC[j], pe0);
            pa0 = fmaf(sa, WaC[j], pa0);
            pe1 = fmaf(sb, WeC[j], pe1);
            pa1 = fmaf(sb, WaC[j], pa1);
        }
        if (ln < 50) {
            spe[whi][0][r5] = pe0; spe[whi][1][r5] = pe1;
            spa[whi][0][r5] = pa0; spa[whi][1][r5] = pa1;
        }
    };

    // ---------- prologue: q(0),q(1),a(0) commits; w(0); s3(0) ----------
    if (is_q) {
        sq[0][qhb][qk] = q_in[(size_t)(blk*2+qhb) * Sd * Kd + qk];
        sq[1][qhb][qk] = q_in[(size_t)(blk*2+qhb) * Sd * Kd + Kd + qk];
    }
    if (is_a) swi[ahb][aj] = a_in[(size_t)(blk*2+ahb) * Sd * Ad + aj];
    __syncthreads();   // S0

    if (wv == 2 || wv == 3) fused_s1s2(0, wv - 2);

    float qreg = 0.f, areg = 0.f;
    if (is_q) qreg = q_in[(size_t)(blk*2+qhb) * Sd * Kd + 2 * Kd + qk];  // q(2)
    if (is_a) areg = a_in[(size_t)(blk*2+ahb) * Sd * Ad + Ad + aj];      // a(1)
    __syncthreads();   // S1

    float swreg = sw[0][hb][ln];
    if (mv < Vd) {
        float p0 = 0.f, p1 = 0.f;
        #pragma unroll
        for (int m = 0; m < Md; m += 2) {
            p0 = fmaf(rl(swreg, m),     memcol[m],     p0);
            p1 = fmaf(rl(swreg, m + 1), memcol[m + 1], p1);
        }
        srcvI[mv * 2 + hb] = p0 + p1;
    }
    if (mv < Md) w_out[(size_t)bidx * Sd * Md + mv] = swreg;

    // ---------- main sequential scan ----------
    for (int t = 0; t < Sd; ++t) {
        __syncthreads();  // B1

        // ---- PhaseA ----
        if (wv >= 4) {
            // s4: rc[a] for a-pair (2g4, 2g4+1), both batches
            float q00 = 0.f, q01 = 0.f, q10 = 0.f, q11 = 0.f;
            #pragma unroll
            for (int j = 0; j < 25; ++j) {
                int v = c4 * 25 + j;
                float2 sv = *(const float2*)&srcvI[v * 2];
                float2 wr = *(const float2*)&sWrT[v * 66 + 2 * g4];
                q00 = fmaf(sv.x, wr.x, q00);
                q01 = fmaf(sv.y, wr.x, q01);
                q10 = fmaf(sv.x, wr.y, q10);
                q11 = fmaf(sv.y, wr.y, q11);
            }
            #pragma unroll
            for (int off = 1; off < 8; off <<= 1) {
                q00 += __shfl_xor(q00, off);
                q01 += __shfl_xor(q01, off);
                q10 += __shfl_xor(q10, off);
                q11 += __shfl_xor(q11, off);
            }
            if (c4 == 0) {
                int a0 = 2 * g4, a1 = a0 + 1;
                float rc00 = q00 + sbr[a0], rc01 = q01 + sbr[a0];
                float rc10 = q10 + sbr[a1], rc11 = q11 + sbr[a1];
                swi[0][64 + a0] = rc00; swi[1][64 + a0] = rc01;
                swi[0][64 + a1] = rc10; swi[1][64 + a1] = rc11;
                size_t o0 = (size_t)(blk*2+0) * Sd * Ad + (size_t)t * Ad;
                size_t o1 = (size_t)(blk*2+1) * Sd * Ad + (size_t)t * Ad;
                rc_out[o0 + a0] = rc00; rc_out[o1 + a0] = rc01;
                rc_out[o0 + a1] = rc10; rc_out[o1 + a1] = rc11;
            }
        } else if (t < Sd - 1) {
            s5dot(0, 0);     // a_t half: inputs available since last commit
        }
        __syncthreads();  // B2

        if (t == Sd - 1) break;

        // ---- PhaseB ----
        if (wv >= 4) {
            s5dot(64, 1);    // rc half
        } else if (wv >= 2) {
            fused_s1s2((t + 1) & 1, wv - 2);   // softmax for t+1, off critical path
        }
        __syncthreads();  // B3

        // ---- PhaseC: s6 + commit(t+1) + s3(t+1) ----
        if (mv < Vd) {
            float ev = sigmoidf_(spe[0][hb][mv] + spe[1][hb][mv] + sbe[mv]);
            float av = fast_tanh(spa[0][hb][mv] + spa[1][hb][mv] + sba[mv]);
            #pragma unroll
            for (int m = 0; m < Md; ++m) {
                float wm = rl(swreg, m);
                memcol[m] = fmaf(wm, fmaf(-ev, memcol[m], av), memcol[m]);
            }
        }
        // commit inputs for step t+1 (consumed after next B1)
        if (is_a) swi[ahb][aj] = areg;
        if (is_q && t + 2 < Sd) sq[(t + 2) & 1][qhb][qk] = qreg;
        // prefetch next inputs
        if (is_a && t + 2 < Sd)
            areg = a_in[(size_t)(blk*2+ahb) * Sd * Ad + (size_t)(t + 2) * Ad + aj];
        if (is_q && t + 3 < Sd)
            qreg = q_in[(size_t)(blk*2+qhb) * Sd * Kd + (size_t)(t + 3) * Kd + qk];
        // s3(t+1): rc_v from updated memcol and w(t+1)
        swreg = sw[(t + 1) & 1][hb][ln];
        if (mv < Vd) {
            float p0 = 0.f, p1 = 0.f;
            #pragma unroll
            for (int m = 0; m < Md; m += 2) {
                p0 = fmaf(rl(swreg, m),     memcol[m],     p0);
                p1 = fmaf(rl(swreg, m + 1), memcol[m + 1], p1);
            }
            srcvI[mv * 2 + hb] = p0 + p1;
        }
        if (mv < Md)
            w_out[(size_t)bidx * Sd * Md + (size_t)(t + 1) * Md + mv] = swreg;
    }

    // ---------- final memory store ----------
    if (mv < Vd) {
        #pragma unroll
        for (int m = 0; m < Md; ++m)
            mem_out[(size_t)bidx * Md * Vd + m * Vd + mv] = memcol[m];
    }
}

extern "C" void kernel_launch(void* const* d_in, const int* in_sizes, int n_in,
                              void* d_out, int out_size, void* d_ws, size_t ws_size,
                              hipStream_t stream) {
    const float* q   = (const float*)d_in[0];
    const float* a   = (const float*)d_in[1];
    const float* mem = (const float*)d_in[2];
    const float* key = (const float*)d_in[3];
    const float* Wc  = (const float*)d_in[4];
    const float* bc  = (const float*)d_in[5];
    const float* Wr  = (const float*)d_in[6];
    const float* br  = (const float*)d_in[7];
    const float* We  = (const float*)d_in[8];
    const float* be  = (const float*)d_in[9];
    const float* Wa  = (const float*)d_in[10];
    const float* ba  = (const float*)d_in[11];

    float* out = (float*)d_out;
    float* rc_out  = out;                                   // (B,S,A)
    float* mem_out = rc_out + (size_t)Bd * Sd * Ad;         // (B,M,V)
    float* w_out   = mem_out + (size_t)Bd * Md * Vd;        // (B,S,M)

    hipLaunchKernelGGL(agm_kernel, dim3(256), dim3(512), 0, stream,
                       q, a, mem, key, Wc, bc, Wr, br, We, be, Wa, ba,
                       rc_out, mem_out, w_out);
}

// Round 2
// 5745.508 us; speedup vs baseline: 1.1038x; 1.0304x over previous
//
#include <hip/hip_runtime.h>
#include <stdint.h>

// Problem dims
#define Md 50
#define Kd 50
#define Vd 200
#define Ad 64
#define Bd 512
#define Sd 1024

__device__ __forceinline__ float fast_tanh(float x) {
    float e = __expf(2.f * x);
    return 1.f - 2.f / (e + 1.f);
}

__device__ __forceinline__ float sigmoidf_(float x) {
    return 1.f / (1.f + __expf(-x));
}

// =====================================================================
// Kernel 1: precompute all softmax weights.
// w(b,t,:) = softmax(tanh(q(b,t,:) @ Wc^T + bc) @ key^T) depends ONLY on q.
// One wave per (b,t) row; 2048 blocks x 256 threads x 64 rows/wave.
// Writes w_out (B,S,M) which is both a kernel output and kernel 2's input.
// =====================================================================
__global__ __launch_bounds__(256)
void wpre_kernel(const float* __restrict__ q_in,
                 const float* __restrict__ key_in,
                 const float* __restrict__ Wc_in,
                 const float* __restrict__ bc_in,
                 float* __restrict__ w_out)
{
    __shared__ float sWc[Kd * 51];    // padded stride 51 (odd) -> 2-way banks
    __shared__ float sKey[Md * 51];
    __shared__ float sbc[Kd];
    __shared__ __align__(16) float sbuf[4][64];

    const int tid = threadIdx.x;
    for (int idx = tid; idx < Kd * Kd; idx += 256) {
        int i = idx / Kd, j = idx % Kd;
        sWc[i * 51 + j]  = Wc_in[idx];
        sKey[i * 51 + j] = key_in[idx];
    }
    if (tid < Kd) sbc[tid] = bc_in[tid];
    __syncthreads();

    const int wv = tid >> 6, ln = tid & 63;
    const int gw = blockIdx.x * 4 + wv;

    for (int r = 0; r < 64; ++r) {
        const size_t row = (size_t)gw * 64 + r;   // flattened (b,t)
        float qv = 0.f;
        if (ln < Kd) qv = q_in[row * Kd + ln];
        sbuf[wv][ln] = qv;
        __syncthreads();

        // ck[ln] = tanh(sum_j q[j] * Wc[ln][j] + bc[ln])
        float ck = 0.f;
        if (ln < Kd) {
            const float4* qp = (const float4*)sbuf[wv];
            float acc = sbc[ln];
            #pragma unroll
            for (int c = 0; c < 12; ++c) {
                float4 x = qp[c];
                acc = fmaf(x.x, sWc[ln * 51 + 4 * c + 0], acc);
                acc = fmaf(x.y, sWc[ln * 51 + 4 * c + 1], acc);
                acc = fmaf(x.z, sWc[ln * 51 + 4 * c + 2], acc);
                acc = fmaf(x.w, sWc[ln * 51 + 4 * c + 3], acc);
            }
            float2 x2 = *(const float2*)&sbuf[wv][48];
            acc = fmaf(x2.x, sWc[ln * 51 + 48], acc);
            acc = fmaf(x2.y, sWc[ln * 51 + 49], acc);
            ck = fast_tanh(acc);
        }
        __syncthreads();
        sbuf[wv][ln] = ck;
        __syncthreads();

        // logits[ln] = sum_k ck[k] * key[ln][k]; softmax over 50
        float lg = -1e30f;
        if (ln < Md) {
            const float4* cp = (const float4*)sbuf[wv];
            float acc = 0.f;
            #pragma unroll
            for (int c = 0; c < 12; ++c) {
                float4 x = cp[c];
                acc = fmaf(x.x, sKey[ln * 51 + 4 * c + 0], acc);
                acc = fmaf(x.y, sKey[ln * 51 + 4 * c + 1], acc);
                acc = fmaf(x.z, sKey[ln * 51 + 4 * c + 2], acc);
                acc = fmaf(x.w, sKey[ln * 51 + 4 * c + 3], acc);
            }
            float2 x2 = *(const float2*)&sbuf[wv][48];
            acc = fmaf(x2.x, sKey[ln * 51 + 48], acc);
            acc = fmaf(x2.y, sKey[ln * 51 + 49], acc);
            lg = acc;
        }
        float mx = lg;
        #pragma unroll
        for (int off = 32; off > 0; off >>= 1)
            mx = fmaxf(mx, __shfl_xor(mx, off));
        float e = (ln < Md) ? __expf(lg - mx) : 0.f;
        float sm = e;
        #pragma unroll
        for (int off = 32; off > 0; off >>= 1)
            sm += __shfl_xor(sm, off);
        if (ln < Md) w_out[row * Md + ln] = e / sm;
        __syncthreads();   // protect sbuf before next row's q write
    }
}

// =====================================================================
// Kernel 2: sequential scan with precomputed w.
// 256 blocks x 512 threads; block handles batches 2*blk, 2*blk+1.
// Per step (3 barriers):
//   P1: ALL waves: erase/add partial dots (full wi available)
//   P2: mem update fused with rv(t+1) accumulation
//   P3: s4 -> rc(t+1) on waves 4-7 || commits/prefetch on waves 0-3
// =====================================================================
__global__ __launch_bounds__(512, 2)
void agm_kernel(const float* __restrict__ a_in,    // (B,S,A)
                const float* __restrict__ mem_in,  // (B,M,V)
                const float* __restrict__ Wr_in,   // (A,V)
                const float* __restrict__ br_in,   // (A)
                const float* __restrict__ We_in,   // (V,2A)
                const float* __restrict__ be_in,   // (V)
                const float* __restrict__ Wa_in,   // (V,2A)
                const float* __restrict__ ba_in,   // (V)
                const float* __restrict__ w_in,    // (B,S,M) precomputed
                float* __restrict__ rc_out,        // (B,S,A)
                float* __restrict__ mem_out)       // (B,M,V)
{
    __shared__ float sWrT[Vd * 66];                 // WrT[v*66+a] = Wr[a][v]
    __shared__ float sbr[Ad];
    __shared__ __align__(16) float swi[2][128];     // [hb]: [0:64)=a_t, [64:128)=rc
    __shared__ __align__(16) float sw[2][2][64];    // [parity][hb][m]
    __shared__ float spe[2][2][Vd];                 // [half][hb][v] erase partials
    __shared__ float spa[2][2][Vd];                 // [half][hb][v] add partials
    __shared__ __align__(8) float srcvI[Vd * 2];    // [v*2 + hb]

    const int tid = threadIdx.x;
    const int blk = blockIdx.x;
    const int hb  = tid >> 8;
    const int mv  = tid & 255;
    const int bidx = blk * 2 + hb;

    // ---------- one-time weight staging ----------
    for (int idx = tid; idx < Ad * Vd; idx += 512) {
        int a = idx / Vd, v = idx % Vd;
        sWrT[v * 66 + a] = Wr_in[idx];
    }
    if (tid < Ad) sbr[tid] = br_in[tid];

    // ---------- register-resident We/Wa half-rows ----------
    // thread tid<400 owns row r5, half wh5 (64 k's) of BOTH We and Wa,
    // and computes partials for BOTH batches.
    const bool isW = (tid < 400);
    const int r5  = tid % 200;
    const int wh5 = tid / 200;     // 0 or 1, valid when isW
    float WeC[64], WaC[64];
    if (isW) {
        const float4* wep = (const float4*)(We_in + (size_t)r5 * 128 + wh5 * 64);
        const float4* wap = (const float4*)(Wa_in + (size_t)r5 * 128 + wh5 * 64);
        #pragma unroll
        for (int c = 0; c < 16; ++c) {
            float4 ue = wep[c], ua = wap[c];
            WeC[4*c+0]=ue.x; WeC[4*c+1]=ue.y; WeC[4*c+2]=ue.z; WeC[4*c+3]=ue.w;
            WaC[4*c+0]=ua.x; WaC[4*c+1]=ua.y; WaC[4*c+2]=ua.z; WaC[4*c+3]=ua.w;
        }
    } else {
        #pragma unroll
        for (int j = 0; j < 64; ++j) { WeC[j] = 0.f; WaC[j] = 0.f; }
    }

    // ---------- register-resident memory column ----------
    const bool isM = (mv < Vd);
    float memcol[Md];
    float ebias = 0.f, abias = 0.f;
    if (isM) {
        #pragma unroll
        for (int m = 0; m < Md; ++m)
            memcol[m] = mem_in[(size_t)bidx * Md * Vd + m * Vd + mv];
        ebias = be_in[mv];
        abias = ba_in[mv];
    } else {
        #pragma unroll
        for (int m = 0; m < Md; ++m) memcol[m] = 0.f;
    }

    // ---------- s4 roles (waves 4-7) ----------
    const int g4 = (tid >> 3) & 31;   // a-pair index
    const int c4 = tid & 7;           // v-chunk (25 wide)

    // ---------- commit/prefetch roles (waves 0-3) ----------
    const bool isA = (tid < 128);
    const int ahb = tid >> 6, aj = tid & 63;
    const bool isWw = (tid >= 128 && tid < 228);
    const int whb = (tid - 128) / 50, wm = (tid - 128) % 50;

    // s4: rc(tt) = Wr @ rv + br; store to swi rc-half and rc_out
    auto s4_phase = [&](int tt) {
        float q00 = 0.f, q01 = 0.f, q10 = 0.f, q11 = 0.f;
        #pragma unroll
        for (int j = 0; j < 25; ++j) {
            int v = c4 * 25 + j;
            float2 sv = *(const float2*)&srcvI[v * 2];
            float2 wr = *(const float2*)&sWrT[v * 66 + 2 * g4];
            q00 = fmaf(sv.x, wr.x, q00);
            q01 = fmaf(sv.y, wr.x, q01);
            q10 = fmaf(sv.x, wr.y, q10);
            q11 = fmaf(sv.y, wr.y, q11);
        }
        #pragma unroll
        for (int off = 1; off < 8; off <<= 1) {
            q00 += __shfl_xor(q00, off);
            q01 += __shfl_xor(q01, off);
            q10 += __shfl_xor(q10, off);
            q11 += __shfl_xor(q11, off);
        }
        if (c4 == 0) {
            int a0 = 2 * g4, a1 = a0 + 1;
            float rc00 = q00 + sbr[a0], rc01 = q01 + sbr[a0];
            float rc10 = q10 + sbr[a1], rc11 = q11 + sbr[a1];
            swi[0][64 + a0] = rc00; swi[1][64 + a0] = rc01;
            swi[0][64 + a1] = rc10; swi[1][64 + a1] = rc11;
            size_t o0 = ((size_t)(blk * 2 + 0) * Sd + tt) * Ad;
            size_t o1 = ((size_t)(blk * 2 + 1) * Sd + tt) * Ad;
            rc_out[o0 + a0] = rc00; rc_out[o1 + a0] = rc01;
            rc_out[o0 + a1] = rc10; rc_out[o1 + a1] = rc11;
        }
    };

    // ---------- prologue ----------
    if (tid < 100) {
        int b = tid / 50, m = tid % 50;
        sw[0][b][m] = w_in[((size_t)(blk * 2 + b) * Sd + 0) * Md + m];
        sw[1][b][m] = w_in[((size_t)(blk * 2 + b) * Sd + 1) * Md + m];
    }
    if (isA) swi[ahb][aj] = a_in[((size_t)(blk * 2 + ahb) * Sd + 0) * Ad + aj];
    float areg = 0.f, wreg = 0.f;
    if (isA) areg = a_in[((size_t)(blk * 2 + ahb) * Sd + 1) * Ad + aj];
    if (isWw) wreg = w_in[((size_t)(blk * 2 + whb) * Sd + 2) * Md + wm];
    __syncthreads();

    // rv(0) = w(0) . memcol
    if (isM) {
        const float4* w0p = (const float4*)sw[0][hb];
        float rv0 = 0.f, rv1 = 0.f;
        #pragma unroll
        for (int c = 0; c < 12; ++c) {
            float4 wa = w0p[c];
            rv0 = fmaf(wa.x, memcol[4*c+0], rv0);
            rv1 = fmaf(wa.y, memcol[4*c+1], rv1);
            rv0 = fmaf(wa.z, memcol[4*c+2], rv0);
            rv1 = fmaf(wa.w, memcol[4*c+3], rv1);
        }
        float2 wa2 = *(const float2*)&sw[0][hb][48];
        rv0 = fmaf(wa2.x, memcol[48], rv0);
        rv1 = fmaf(wa2.y, memcol[49], rv1);
        srcvI[mv * 2 + hb] = rv0 + rv1;
    }
    __syncthreads();
    if (tid >= 256) s4_phase(0);
    __syncthreads();

    // ---------- main scan: t = 0 .. Sd-2 (1023 memory writes) ----------
    for (int t = 0; t < Sd - 1; ++t) {
        // ---- P1: erase/add partial dots, all waves ----
        if (isW) {
            const float4* x0p = (const float4*)&swi[0][wh5 * 64];
            const float4* x1p = (const float4*)&swi[1][wh5 * 64];
            float pe0 = 0.f, pa0 = 0.f, pe1 = 0.f, pa1 = 0.f;
            #pragma unroll
            for (int c = 0; c < 16; ++c) {
                float4 x0 = x0p[c];
                float4 x1 = x1p[c];
                float w0 = WeC[4*c+0], w1 = WeC[4*c+1], w2 = WeC[4*c+2], w3 = WeC[4*c+3];
                float u0 = WaC[4*c+0], u1 = WaC[4*c+1], u2 = WaC[4*c+2], u3 = WaC[4*c+3];
                pe0 = fmaf(x0.x, w0, pe0); pe0 = fmaf(x0.y, w1, pe0);
                pe0 = fmaf(x0.z, w2, pe0); pe0 = fmaf(x0.w, w3, pe0);
                pa0 = fmaf(x0.x, u0, pa0); pa0 = fmaf(x0.y, u1, pa0);
                pa0 = fmaf(x0.z, u2, pa0); pa0 = fmaf(x0.w, u3, pa0);
                pe1 = fmaf(x1.x, w0, pe1); pe1 = fmaf(x1.y, w1, pe1);
                pe1 = fmaf(x1.z, w2, pe1); pe1 = fmaf(x1.w, w3, pe1);
                pa1 = fmaf(x1.x, u0, pa1); pa1 = fmaf(x1.y, u1, pa1);
                pa1 = fmaf(x1.z, u2, pa1); pa1 = fmaf(x1.w, u3, pa1);
            }
            spe[wh5][0][r5] = pe0; spe[wh5][1][r5] = pe1;
            spa[wh5][0][r5] = pa0; spa[wh5][1][r5] = pa1;
        }
        __syncthreads();  // B1

        // ---- P2: mem update + rv(t+1), fused single pass ----
        if (isM) {
            float se_ = spe[0][hb][mv] + spe[1][hb][mv] + ebias;
            float sa_ = spa[0][hb][mv] + spa[1][hb][mv] + abias;
            float ev = sigmoidf_(se_);
            float av = fast_tanh(sa_);
            const float4* w0p = (const float4*)sw[t & 1][hb];
            const float4* w1p = (const float4*)sw[(t + 1) & 1][hb];
            float rv0 = 0.f, rv1 = 0.f;
            #pragma unroll
            for (int c = 0; c < 12; ++c) {
                float4 wa = w0p[c];
                float4 wb = w1p[c];
                { float mc = memcol[4*c+0]; mc = fmaf(wa.x, fmaf(-ev, mc, av), mc);
                  memcol[4*c+0] = mc; rv0 = fmaf(wb.x, mc, rv0); }
                { float mc = memcol[4*c+1]; mc = fmaf(wa.y, fmaf(-ev, mc, av), mc);
                  memcol[4*c+1] = mc; rv1 = fmaf(wb.y, mc, rv1); }
                { float mc = memcol[4*c+2]; mc = fmaf(wa.z, fmaf(-ev, mc, av), mc);
                  memcol[4*c+2] = mc; rv0 = fmaf(wb.z, mc, rv0); }
                { float mc = memcol[4*c+3]; mc = fmaf(wa.w, fmaf(-ev, mc, av), mc);
                  memcol[4*c+3] = mc; rv1 = fmaf(wb.w, mc, rv1); }
            }
            {
                float2 wa2 = *(const float2*)&sw[t & 1][hb][48];
                float2 wb2 = *(const float2*)&sw[(t + 1) & 1][hb][48];
                { float mc = memcol[48]; mc = fmaf(wa2.x, fmaf(-ev, mc, av), mc);
                  memcol[48] = mc; rv0 = fmaf(wb2.x, mc, rv0); }
                { float mc = memcol[49]; mc = fmaf(wa2.y, fmaf(-ev, mc, av), mc);
                  memcol[49] = mc; rv1 = fmaf(wb2.y, mc, rv1); }
            }
            srcvI[mv * 2 + hb] = rv0 + rv1;
        }
        __syncthreads();  // B2

        // ---- P3: rc(t+1) on waves 4-7 || commits on waves 0-3 ----
        if (tid >= 256) {
            s4_phase(t + 1);
        } else {
            if (isA) swi[ahb][aj] = areg;                       // a(t+1)
            if (isWw && t + 2 < Sd) sw[t & 1][whb][wm] = wreg;  // w(t+2)
        }
        if (isA && t + 2 < Sd)
            areg = a_in[((size_t)(blk * 2 + ahb) * Sd + (t + 2)) * Ad + aj];
        if (isWw && t + 3 < Sd)
            wreg = w_in[((size_t)(blk * 2 + whb) * Sd + (t + 3)) * Md + wm];
        __syncthreads();  // B3
    }

    // ---------- final memory store ----------
    if (isM) {
        #pragma unroll
        for (int m = 0; m < Md; ++m)
            mem_out[(size_t)bidx * Md * Vd + m * Vd + mv] = memcol[m];
    }
}

extern "C" void kernel_launch(void* const* d_in, const int* in_sizes, int n_in,
                              void* d_out, int out_size, void* d_ws, size_t ws_size,
                              hipStream_t stream) {
    const float* q   = (const float*)d_in[0];
    const float* a   = (const float*)d_in[1];
    const float* mem = (const float*)d_in[2];
    const float* key = (const float*)d_in[3];
    const float* Wc  = (const float*)d_in[4];
    const float* bc  = (const float*)d_in[5];
    const float* Wr  = (const float*)d_in[6];
    const float* br  = (const float*)d_in[7];
    const float* We  = (const float*)d_in[8];
    const float* be  = (const float*)d_in[9];
    const float* Wa  = (const float*)d_in[10];
    const float* ba  = (const float*)d_in[11];

    float* out = (float*)d_out;
    float* rc_out  = out;                                   // (B,S,A)
    float* mem_out = rc_out + (size_t)Bd * Sd * Ad;         // (B,M,V)
    float* w_out   = mem_out + (size_t)Bd * Md * Vd;        // (B,S,M)

    // Phase 1: fully parallel softmax-weight precompute (writes w_out).
    hipLaunchKernelGGL(wpre_kernel, dim3(2048), dim3(256), 0, stream,
                       q, key, Wc, bc, w_out);
    // Phase 2: sequential scan consuming w_out.
    hipLaunchKernelGGL(agm_kernel, dim3(256), dim3(512), 0, stream,
                       a, mem, Wr, br, We, be, Wa, ba, w_out,
                       rc_out, mem_out);
}